// Round 6
// baseline (861.103 us; speedup 1.0000x reference)
//
#include <hip/hip_runtime.h>
#include <hip/hip_bf16.h>
#include <stdint.h>

// DTYPE CONTRACT (locked R3): inputs f32, output f32 [loss, probs(128000)].
// WS MAP (223,248,000 B budget proven R3):
//   [0, 26.6M)        w_ws fp32 [row][52]  (k_w -> k_scan); after k_scan dead:
//                       parts @ +0 (16KB), wr_bf @ +16.0M, q_bf @ +2.0M (k_cvt2 -> k_final)
//   [26.6M, 157.7M)   ea_ws bf16 [row][512] (k_ea -> k_scan)
//   [157.7M, 223.2M)   union: qa_bf (51.2M) + Wcomb bf16 (256KB) (k_cvt -> k_ea),
//                     then reads_ws bf16 (k_scan -> k_final)

#define BATCH 256
#define TLEN  500
#define DKQ   128
#define DVV   256
#define MSZ   50
#define NROWS 128000
#define GSZ   10

__device__ __forceinline__ float bfs(uint16_t u){
  union { uint32_t u; float f; } v; v.u = ((uint32_t)u) << 16; return v.f;
}
__device__ __forceinline__ uint16_t f2b(float x){
  union { __hip_bfloat16 h; uint16_t u; } c; c.h = __float2bfloat16(x); return c.u;
}

typedef __attribute__((ext_vector_type(8))) short bf16x8;
typedef __attribute__((ext_vector_type(4))) float f32x4;

__device__ __forceinline__ void gl_lds16(const void* g, void* l){
  __builtin_amdgcn_global_load_lds(
      (const __attribute__((address_space(1))) void*)g,
      (__attribute__((address_space(3))) void*)l, 16, 0, 0);
}

// =====================================================================
// K1a: w = softmax(q_e @ Mk^T) -> w_ws fp32 [row][52]  (unchanged)
// =====================================================================
__global__ __launch_bounds__(128, 1) void k_w(
    const int* __restrict__ q_data, const float* __restrict__ q_tab,
    const float* __restrict__ Mk, float* __restrict__ w_ws)
{
  __shared__ float mk[MSZ*DKQ];
  __shared__ float wt[128*52];
  const int tid = threadIdx.x;
  for (int li = tid; li < 1600; li += 128)
    ((float4*)mk)[li] = ((const float4*)Mk)[li];
  __syncthreads();

  const int row = blockIdx.x*128 + tid;
  const int qi = q_data[row];
  const float4* qrow = (const float4*)(q_tab + (size_t)qi*DKQ);

  float acc[MSZ];
  #pragma unroll
  for (int m=0;m<MSZ;m++) acc[m] = 0.f;

  #pragma unroll 1
  for (int c8=0; c8<8; c8++){
    float4 q0 = qrow[c8*4+0], q1 = qrow[c8*4+1], q2 = qrow[c8*4+2], q3 = qrow[c8*4+3];
    #pragma unroll
    for (int m=0;m<MSZ;m++){
      const float4* mr = (const float4*)&mk[m*DKQ + c8*16];
      float4 a = mr[0], b = mr[1], cc = mr[2], d = mr[3];
      float s = acc[m];
      s = fmaf(q0.x,a.x,s);  s = fmaf(q0.y,a.y,s);  s = fmaf(q0.z,a.z,s);  s = fmaf(q0.w,a.w,s);
      s = fmaf(q1.x,b.x,s);  s = fmaf(q1.y,b.y,s);  s = fmaf(q1.z,b.z,s);  s = fmaf(q1.w,b.w,s);
      s = fmaf(q2.x,cc.x,s); s = fmaf(q2.y,cc.y,s); s = fmaf(q2.z,cc.z,s); s = fmaf(q2.w,cc.w,s);
      s = fmaf(q3.x,d.x,s);  s = fmaf(q3.y,d.y,s);  s = fmaf(q3.z,d.z,s);  s = fmaf(q3.w,d.w,s);
      acc[m] = s;
    }
  }
  float mx = acc[0];
  #pragma unroll
  for (int m=1;m<MSZ;m++) mx = fmaxf(mx, acc[m]);
  float s = 0.f;
  #pragma unroll
  for (int m=0;m<MSZ;m++){ acc[m] = __expf(acc[m]-mx); s += acc[m]; }
  float inv = 1.0f / s;
  #pragma unroll
  for (int m=0;m<MSZ;m++) wt[tid*52+m] = acc[m]*inv;
  wt[tid*52+50] = 0.f; wt[tid*52+51] = 0.f;   // zero pad -> masking-free k_scan
  __syncthreads();
  float4* dst = (float4*)(w_ws + (size_t)blockIdx.x*128*52);
  const float4* src = (const float4*)wt;
  for (int li = tid; li < 1664; li += 128) dst[li] = src[li];
}

// =====================================================================
// K-cvt: qa_tab f32 -> bf16  AND  Wcomb = [We|Wa] f32 -> bf16  (unchanged)
// =====================================================================
__global__ __launch_bounds__(256) void k_cvt(
    const float* __restrict__ qa_tab, const float* __restrict__ We,
    const float* __restrict__ Wa, uint16_t* __restrict__ qa_bf,
    uint16_t* __restrict__ wcomb)
{
  const size_t n_qa4 = 6400064;            // 100001*256/4
  const size_t n_w4  = 32768;              // 512*256/4
  size_t stride = (size_t)gridDim.x*blockDim.x;
  for (size_t i = (size_t)blockIdx.x*256 + threadIdx.x; i < n_qa4 + n_w4; i += stride){
    float4 v;
    if (i < n_qa4){
      v = ((const float4*)qa_tab)[i];
      ushort4 o; o.x=f2b(v.x); o.y=f2b(v.y); o.z=f2b(v.z); o.w=f2b(v.w);
      ((ushort4*)qa_bf)[i] = o;
    } else {
      size_t j = i - n_qa4;                // float4 index into Wcomb [512][256]
      size_t f = j*4;
      int col = (int)(f >> 8), k = (int)(f & 255);
      const float* srcp = (col < 256) ? (We + (size_t)col*256 + k)
                                      : (Wa + (size_t)(col-256)*256 + k);
      v = *(const float4*)srcp;
      ushort4 o; o.x=f2b(v.x); o.y=f2b(v.y); o.z=f2b(v.z); o.w=f2b(v.w);
      ((ushort4*)wcomb)[j] = o;
    }
  }
}

// =====================================================================
// K-cvt2 (after k_scan, into dead w_ws region): q_tab -> q_bf, Wr -> wr_bf
// =====================================================================
__global__ __launch_bounds__(256) void k_cvt2(
    const float* __restrict__ q_tab, const float* __restrict__ Wr,
    uint16_t* __restrict__ q_bf, uint16_t* __restrict__ wr_bf)
{
  const size_t n_q4  = 1600032;            // 50001*128/4
  const size_t n_wr4 = 12288;              // 128*384/4
  size_t stride = (size_t)gridDim.x*blockDim.x;
  for (size_t i = (size_t)blockIdx.x*256 + threadIdx.x; i < n_q4 + n_wr4; i += stride){
    if (i < n_q4){
      float4 v = ((const float4*)q_tab)[i];
      ushort4 o; o.x=f2b(v.x); o.y=f2b(v.y); o.z=f2b(v.z); o.w=f2b(v.w);
      ((ushort4*)q_bf)[i] = o;
    } else {
      size_t j = i - n_q4;
      float4 v = ((const float4*)Wr)[j];
      ushort4 o; o.x=f2b(v.x); o.y=f2b(v.y); o.z=f2b(v.z); o.w=f2b(v.w);
      ((ushort4*)wr_bf)[j] = o;
    }
  }
}

// =====================================================================
// K1b: ea via bf16 MFMA; all staging via global_load_lds (unchanged)
// =====================================================================
__global__ __launch_bounds__(256, 2) void k_ea(
    const int* __restrict__ qa_data, const uint16_t* __restrict__ qa_bf,
    const uint16_t* __restrict__ wcomb, const float* __restrict__ be,
    const float* __restrict__ ba, __hip_bfloat16* __restrict__ ea_ws)
{
  __shared__ uint16_t Ab[128*32];
  __shared__ uint16_t Bb[128*32];
  const int tid = threadIdx.x;
  const int lane = tid & 63, wid = tid >> 6;
  const int braw = blockIdx.x;
  const int nb = (braw >> 3) & 3;                      // col-block
  const int mb = (braw & 7) | ((braw >> 5) << 3);      // row-block; siblings: b,b+8,b+16,b+24 -> same XCD (b%8)
  const int rb = mb*128, cb = nb*128;

  const char* qac = (const char*)qa_bf;
  size_t aoff0, aoff1;
  {
    int r0 = wid*32 + (lane>>2);
    aoff0 = (size_t)qa_data[rb + r0]*512      + (size_t)(lane&3)*16;
    aoff1 = (size_t)qa_data[rb + r0 + 16]*512 + (size_t)(lane&3)*16;
  }
  const char* wcb = (const char*)wcomb;
  size_t boff0 = (size_t)(cb + wid*32 + (lane>>2))*512 + (size_t)(lane&3)*16;
  size_t boff1 = boff0 + 16*512;

  const int wr = (wid>>1)*64, wc = (wid&1)*64;
  float bias[4];
  #pragma unroll
  for (int tj=0;tj<4;tj++){
    int colg = cb + wc + tj*16 + (lane&15);
    bias[tj] = (nb<2) ? be[colg] : ba[colg-256];
  }

  f32x4 acc[4][4];
  #pragma unroll
  for (int i=0;i<4;i++){
    #pragma unroll
    for (int j=0;j<4;j++) acc[i][j] = (f32x4)(0.f);
  }

  #pragma unroll 1
  for (int kc=0; kc<8; kc++){
    __syncthreads();
    gl_lds16(qac + aoff0 + (size_t)kc*64, &Ab[(wid*2+0)*512]);
    gl_lds16(qac + aoff1 + (size_t)kc*64, &Ab[(wid*2+1)*512]);
    gl_lds16(wcb + boff0 + (size_t)kc*64, &Bb[(wid*2+0)*512]);
    gl_lds16(wcb + boff1 + (size_t)kc*64, &Bb[(wid*2+1)*512]);
    __syncthreads();
    bf16x8 af[4], bfr[4];
    #pragma unroll
    for (int ti=0;ti<4;ti++)
      af[ti] = *(const bf16x8*)&Ab[(wr + ti*16 + (lane&15))*32 + (lane>>4)*8];
    #pragma unroll
    for (int tj=0;tj<4;tj++)
      bfr[tj] = *(const bf16x8*)&Bb[(wc + tj*16 + (lane&15))*32 + (lane>>4)*8];
    #pragma unroll
    for (int ti=0;ti<4;ti++){
      #pragma unroll
      for (int tj=0;tj<4;tj++)
        acc[ti][tj] = __builtin_amdgcn_mfma_f32_16x16x32_bf16(af[ti], bfr[tj], acc[ti][tj], 0, 0, 0);
    }
  }
  const int rq = (lane>>4)*4, cl = lane&15;
  #pragma unroll
  for (int ti=0;ti<4;ti++){
    #pragma unroll
    for (int r=0;r<4;r++){
      int row = rb + wr + ti*16 + rq + r;
      __hip_bfloat16* orow = ea_ws + (size_t)row*512 + cb + wc;
      #pragma unroll
      for (int tj=0;tj<4;tj++){
        float x = acc[ti][tj][r] + bias[tj];
        float v = (nb<2) ? (1.f/(1.f+__expf(-x)))
                         : (1.f - 2.f/(__expf(2.f*x)+1.f));
        orow[tj*16 + cl] = __float2bfloat16(v);
      }
    }
  }
}

// =====================================================================
// K2 v11: FULL-m per thread (R5 structure) + w in SGPRs, SINGLE-buffered.
// R5 post-mortem: VGPR_Count=144 vs demand 156+ (Mv 52 + 2x52 w dbuf) ->
// AGPR spills (v_accvgpr_* are VALU) -> ~960 VALU cyc/step vs ~340 needed.
// Fix: w is block-uniform -> load via address_space(4) (R4-proven path) so
// it lands in SGPRs via s_load_dwordx4 and is consumed directly as the
// scalar operand of v_fma. SINGLE buffer wv[13] (52 SGPR), explicit order:
//   step t: [read-FMAs use wv] [store read] [gated update, last wv use]
//           [reload wv <- w(t+1)]   (per-quad reload floats up behind its
//           last update; residual SMEM stall ~100-200 cyc hides the rest)
// Register demand: ~90 VGPR (Mv 52 + e/a 20 + misc), ~75 SGPR -> no spill.
// Zero LDS, zero barriers, zero exchange (unchanged). 1 wave/SIMD by design.
// =====================================================================
__global__ __launch_bounds__(256, 1) void k_scan(
    const int* __restrict__ q_data, const float* __restrict__ w_ws,
    const uint16_t* __restrict__ ea_ws, const float* __restrict__ Mv0,
    __hip_bfloat16* __restrict__ reads_ws)
{
  const int d    = threadIdx.x;     // 0..255
  const int b    = blockIdx.x;      // 0..255
  const int base = b * TLEN;

  float Mv[52];
  #pragma unroll
  for (int m=0;m<MSZ;m++) Mv[m] = Mv0[(size_t)m*256 + d];
  Mv[50] = 0.f; Mv[51] = 0.f;

  typedef const __attribute__((address_space(4))) int   cint;
  typedef const __attribute__((address_space(4))) float cfloat;
  typedef const __attribute__((address_space(4))) f32x4 cf32x4;
  cint*   qbase = (cint*)q_data + base;
  cfloat* wbase = (cfloat*)w_ws + (size_t)base*52;

  // w single buffer (SGPRs): prologue load of t=0
  f32x4 wv[13];
  #pragma unroll
  for (int qq=0;qq<13;qq++) wv[qq] = ((cf32x4*)wbase)[qq];

  uint32_t epk[GSZ], epn[GSZ];
  #pragma unroll
  for (int j=0;j<GSZ;j++){
    uint32_t e16 = ea_ws[(size_t)(base+j)*512 + d];
    uint32_t a16 = ea_ws[(size_t)(base+j)*512 + 256 + d];
    epk[j] = (a16 << 16) | e16;
  }

  #pragma unroll 1
  for (int g=0; g<50; g++){
    if (g < 49){
      const int sn = base + (g+1)*GSZ;
      #pragma unroll
      for (int j=0;j<GSZ;j++){
        uint32_t e16 = ea_ws[(size_t)(sn+j)*512 + d];
        uint32_t a16 = ea_ws[(size_t)(sn+j)*512 + 256 + d];
        epn[j] = (a16 << 16) | e16;
      }
    }
    int qv[GSZ];
    #pragma unroll
    for (int j=0;j<GSZ;j++) qv[j] = qbase[g*GSZ + j];   // scalar gate (SMEM)

    #pragma unroll
    for (int jj=0; jj<GSZ; jj++){
      const uint32_t p = epk[jj];
      union { uint32_t u; float f; } ue_, ua_;
      ue_.u = p << 16; ua_.u = p & 0xffff0000u;
      const float ef = ue_.f, af = ua_.f;

      float r0=0.f, r1=0.f, r2=0.f, r3=0.f;
      #pragma unroll
      for (int qq=0;qq<13;qq++){
        r0 = fmaf(wv[qq].x, Mv[qq*4+0], r0);
        r1 = fmaf(wv[qq].y, Mv[qq*4+1], r1);
        r2 = fmaf(wv[qq].z, Mv[qq*4+2], r2);
        r3 = fmaf(wv[qq].w, Mv[qq*4+3], r3);
      }
      reads_ws[(size_t)(base + g*GSZ + jj)*256 + d] =
          __float2bfloat16((r0+r1)+(r2+r3));

      if (qv[jj] > 0){   // uniform branch; q==0 is ~1/50001 per element
        #pragma unroll
        for (int qq=0;qq<13;qq++){
          { float tt = fmaf(ef, Mv[qq*4+0], -af); Mv[qq*4+0] = fmaf(-wv[qq].x, tt, Mv[qq*4+0]); }
          { float tt = fmaf(ef, Mv[qq*4+1], -af); Mv[qq*4+1] = fmaf(-wv[qq].y, tt, Mv[qq*4+1]); }
          { float tt = fmaf(ef, Mv[qq*4+2], -af); Mv[qq*4+2] = fmaf(-wv[qq].z, tt, Mv[qq*4+2]); }
          { float tt = fmaf(ef, Mv[qq*4+3], -af); Mv[qq*4+3] = fmaf(-wv[qq].w, tt, Mv[qq*4+3]); }
        }
      }

      // reload wv with w(t+1) AFTER its last use (single buffer, WAR-safe);
      // per-quad loads can float up behind that quad's final update.
      int tn = g*GSZ + jj + 1; if (tn > TLEN-1) tn = TLEN-1;
      cf32x4* wq = (cf32x4*)(wbase + (size_t)tn*52);
      #pragma unroll
      for (int qq=0;qq<13;qq++) wv[qq] = wq[qq];
    }

    if (g < 49){
      #pragma unroll
      for (int j=0;j<GSZ;j++) epk[j] = epn[j];
    }
  }
}

// =====================================================================
// K3 v3: bf16 MFMA, all staging via global_load_lds (unchanged)
// =====================================================================
__global__ __launch_bounds__(256, 2) void k_final(
    const int* __restrict__ q_data, const uint16_t* __restrict__ q_bf,
    const uint16_t* __restrict__ reads16, const uint16_t* __restrict__ wr_bf,
    const float* __restrict__ br, const float* __restrict__ Wp,
    const float* __restrict__ bp, const float* __restrict__ target,
    float* __restrict__ out, float* __restrict__ parts)
{
  __shared__ uint16_t Ab[64*32];    // 4 KB
  __shared__ uint16_t Bb[128*32];   // 8 KB
  __shared__ float redbuf[8];
  const int tid = threadIdx.x;
  const int lane = tid & 63, wid = tid >> 6;
  const int rb = blockIdx.x * 64;

  const char* rdc = (const char*)reads16;
  const char* qbc = (const char*)q_bf;
  const char* wrc = (const char*)wr_bf;
  const int arow = wid*16 + (lane>>2);
  size_t aoff_r = (size_t)(rb+arow)*512 + (size_t)(lane&3)*16;
  size_t aoff_q = (size_t)q_data[rb+arow]*256 + (size_t)(lane&3)*16;
  size_t boff0  = (size_t)(wid*32 + (lane>>2))*768 + (size_t)(lane&3)*16;
  size_t boff1  = boff0 + 16*768;

  f32x4 acc[8];
  #pragma unroll
  for (int tj=0;tj<8;tj++) acc[tj] = (f32x4)(0.f);

  #pragma unroll 1
  for (int kc=0; kc<12; kc++){
    __syncthreads();
    if (kc < 8) gl_lds16(rdc + aoff_r + (size_t)kc*64,     &Ab[wid*512]);
    else        gl_lds16(qbc + aoff_q + (size_t)(kc-8)*64, &Ab[wid*512]);
    gl_lds16(wrc + boff0 + (size_t)kc*64, &Bb[(wid*2+0)*512]);
    gl_lds16(wrc + boff1 + (size_t)kc*64, &Bb[(wid*2+1)*512]);
    __syncthreads();
    bf16x8 af = *(const bf16x8*)&Ab[(wid*16 + (lane&15))*32 + (lane>>4)*8];
    #pragma unroll
    for (int tj=0;tj<8;tj++){
      bf16x8 bf = *(const bf16x8*)&Bb[(tj*16 + (lane&15))*32 + (lane>>4)*8];
      acc[tj] = __builtin_amdgcn_mfma_f32_16x16x32_bf16(af, bf, acc[tj], 0, 0, 0);
    }
  }
  const int cl = lane & 15, rq = lane >> 4;
  float p[4] = {0.f,0.f,0.f,0.f};
  #pragma unroll
  for (int tj=0;tj<8;tj++){
    int cg = tj*16 + cl;
    float brv = br[cg], wpv = Wp[cg];
    #pragma unroll
    for (int r=0;r<4;r++){
      float x = acc[tj][r] + brv;
      float hh = 1.f - 2.f/(__expf(2.f*x)+1.f);
      p[r] = fmaf(hh, wpv, p[r]);
    }
  }
  #pragma unroll
  for (int off=1; off<16; off<<=1){
    #pragma unroll
    for (int r=0;r<4;r++) p[r] += __shfl_xor(p[r], off);
  }
  float bpv = bp[0];
  float lsum = 0.f, csum = 0.f;
  if (cl == 0){
    #pragma unroll
    for (int r=0;r<4;r++){
      int row = rb + wid*16 + rq*4 + r;
      float pred = p[r] + bpv;
      out[1 + row] = 1.f/(1.f + __expf(-pred));
      float tg = target[row];
      if (tg >= 0.f){
        lsum += fmaxf(pred, 0.f) - pred*tg + log1pf(__expf(-fabsf(pred)));
        csum += 1.f;
      }
    }
  }
  #pragma unroll
  for (int off=16; off<64; off<<=1){
    lsum += __shfl_xor(lsum, off);
    csum += __shfl_xor(csum, off);
  }
  if (lane == 0){ redbuf[wid*2] = lsum; redbuf[wid*2+1] = csum; }
  __syncthreads();
  if (tid == 0){
    parts[blockIdx.x]        = redbuf[0]+redbuf[2]+redbuf[4]+redbuf[6];
    parts[2000 + blockIdx.x] = redbuf[1]+redbuf[3]+redbuf[5]+redbuf[7];
  }
}

// =====================================================================
// K4: final loss reduction (unchanged)
// =====================================================================
__global__ __launch_bounds__(256) void k_loss(
    const float* __restrict__ parts, float* __restrict__ out)
{
  __shared__ float red[8];
  const int tid = threadIdx.x;
  float l = 0.f, cn = 0.f;
  for (int i = tid; i < 2000; i += 256){ l += parts[i]; cn += parts[2000+i]; }
  #pragma unroll
  for (int off=32; off>0; off>>=1){ l += __shfl_xor(l, off); cn += __shfl_xor(cn, off); }
  if ((tid & 63) == 0){ red[(tid>>6)*2] = l; red[(tid>>6)*2+1] = cn; }
  __syncthreads();
  if (tid == 0){
    float L = red[0]+red[2]+red[4]+red[6];
    float C = red[1]+red[3]+red[5]+red[7];
    out[0] = L / fmaxf(C, 1.f);
  }
}

// =====================================================================
extern "C" void kernel_launch(void* const* d_in, const int* in_sizes, int n_in,
                              void* d_out, int out_size, void* d_ws, size_t ws_size,
                              hipStream_t stream) {
  const int*   q_data  = (const int*)d_in[0];
  const int*   qa_data = (const int*)d_in[1];
  const float* target  = (const float*)d_in[2];
  const float* q_tab   = (const float*)d_in[3];
  const float* qa_tab  = (const float*)d_in[4];
  const float* Mk  = (const float*)d_in[5];
  const float* Mv0 = (const float*)d_in[6];
  const float* We  = (const float*)d_in[7];
  const float* be  = (const float*)d_in[8];
  const float* Wa  = (const float*)d_in[9];
  const float* ba  = (const float*)d_in[10];
  const float* Wr  = (const float*)d_in[11];
  const float* br  = (const float*)d_in[12];
  const float* Wp  = (const float*)d_in[13];
  const float* bp  = (const float*)d_in[14];

  char* ws = (char*)d_ws;
  float*          w_ws     = (float*)ws;                           // [0, 26,624,000)
  __hip_bfloat16* ea_ws    = (__hip_bfloat16*)(ws + 26624000);     // 131,072,000 B
  uint16_t*       qa_bf    = (uint16_t*)(ws + 157696000);          // 51,200,512 B
  uint16_t*       wcomb    = (uint16_t*)(ws + 208896512);          // 262,144 B
  __hip_bfloat16* reads_ws = (__hip_bfloat16*)(ws + 157696000);    // 65,536,000 B (after k_ea)
  float*          parts    = (float*)ws;                           // 16,000 B (after k_scan)
  uint16_t*       q_bf     = (uint16_t*)(ws + 2000000);            // 12,800,256 B (after k_scan)
  uint16_t*       wr_bf    = (uint16_t*)(ws + 16000000);           // 98,304 B (after k_scan)

  float* out = (float*)d_out;   // f32: [loss, probs(128000)]

  k_w    <<<1000, 128, 0, stream>>>(q_data, q_tab, Mk, w_ws);
  k_cvt  <<<2048, 256, 0, stream>>>(qa_tab, We, Wa, qa_bf, wcomb);
  k_ea   <<<4000, 256, 0, stream>>>(qa_data, qa_bf, wcomb, be, ba, ea_ws);
  k_scan <<<256,  256, 0, stream>>>(q_data, w_ws, (const uint16_t*)ea_ws, Mv0, reads_ws);
  k_cvt2 <<<1024, 256, 0, stream>>>(q_tab, Wr, q_bf, wr_bf);
  k_final<<<2000, 256, 0, stream>>>(q_data, q_bf, (const uint16_t*)reads_ws, wr_bf, br, Wp, bp, target, out, parts);
  k_loss <<<1,    256, 0, stream>>>(parts, out);
}

// Round 7
// 701.650 us; speedup vs baseline: 1.2273x; 1.2273x over previous
//
#include <hip/hip_runtime.h>
#include <hip/hip_bf16.h>
#include <stdint.h>

// DTYPE CONTRACT (locked R3): inputs f32, output f32 [loss, probs(128000)].
// WS MAP (223,248,000 B budget proven R3):
//   [0, 26.6M)        w_ws fp32 [row][52]  (k_w -> k_scan); after k_scan dead:
//                       parts @ +0 (16KB), wr_bf @ +16.0M, q_bf @ +2.0M (k_cvt2 -> k_final)
//   [26.6M, 157.7M)   ea_ws bf16 [row][512] (k_ea -> k_scan)
//   [157.7M, 223.2M)   union: qa_bf (51.2M) + Wcomb bf16 (256KB) (k_cvt -> k_ea),
//                     then reads_ws bf16 (k_scan -> k_final)

#define BATCH 256
#define TLEN  500
#define DKQ   128
#define DVV   256
#define MSZ   50
#define NROWS 128000
#define GSZ   10

__device__ __forceinline__ float bfs(uint16_t u){
  union { uint32_t u; float f; } v; v.u = ((uint32_t)u) << 16; return v.f;
}
__device__ __forceinline__ uint16_t f2b(float x){
  union { __hip_bfloat16 h; uint16_t u; } c; c.h = __float2bfloat16(x); return c.u;
}

typedef __attribute__((ext_vector_type(8))) short bf16x8;
typedef __attribute__((ext_vector_type(4))) float f32x4;

__device__ __forceinline__ void gl_lds16(const void* g, void* l){
  __builtin_amdgcn_global_load_lds(
      (const __attribute__((address_space(1))) void*)g,
      (__attribute__((address_space(3))) void*)l, 16, 0, 0);
}

// =====================================================================
// K1a: w = softmax(q_e @ Mk^T) -> w_ws fp32 [row][52]  (unchanged)
// =====================================================================
__global__ __launch_bounds__(128, 1) void k_w(
    const int* __restrict__ q_data, const float* __restrict__ q_tab,
    const float* __restrict__ Mk, float* __restrict__ w_ws)
{
  __shared__ float mk[MSZ*DKQ];
  __shared__ float wt[128*52];
  const int tid = threadIdx.x;
  for (int li = tid; li < 1600; li += 128)
    ((float4*)mk)[li] = ((const float4*)Mk)[li];
  __syncthreads();

  const int row = blockIdx.x*128 + tid;
  const int qi = q_data[row];
  const float4* qrow = (const float4*)(q_tab + (size_t)qi*DKQ);

  float acc[MSZ];
  #pragma unroll
  for (int m=0;m<MSZ;m++) acc[m] = 0.f;

  #pragma unroll 1
  for (int c8=0; c8<8; c8++){
    float4 q0 = qrow[c8*4+0], q1 = qrow[c8*4+1], q2 = qrow[c8*4+2], q3 = qrow[c8*4+3];
    #pragma unroll
    for (int m=0;m<MSZ;m++){
      const float4* mr = (const float4*)&mk[m*DKQ + c8*16];
      float4 a = mr[0], b = mr[1], cc = mr[2], d = mr[3];
      float s = acc[m];
      s = fmaf(q0.x,a.x,s);  s = fmaf(q0.y,a.y,s);  s = fmaf(q0.z,a.z,s);  s = fmaf(q0.w,a.w,s);
      s = fmaf(q1.x,b.x,s);  s = fmaf(q1.y,b.y,s);  s = fmaf(q1.z,b.z,s);  s = fmaf(q1.w,b.w,s);
      s = fmaf(q2.x,cc.x,s); s = fmaf(q2.y,cc.y,s); s = fmaf(q2.z,cc.z,s); s = fmaf(q2.w,cc.w,s);
      s = fmaf(q3.x,d.x,s);  s = fmaf(q3.y,d.y,s);  s = fmaf(q3.z,d.z,s);  s = fmaf(q3.w,d.w,s);
      acc[m] = s;
    }
  }
  float mx = acc[0];
  #pragma unroll
  for (int m=1;m<MSZ;m++) mx = fmaxf(mx, acc[m]);
  float s = 0.f;
  #pragma unroll
  for (int m=0;m<MSZ;m++){ acc[m] = __expf(acc[m]-mx); s += acc[m]; }
  float inv = 1.0f / s;
  #pragma unroll
  for (int m=0;m<MSZ;m++) wt[tid*52+m] = acc[m]*inv;
  wt[tid*52+50] = 0.f; wt[tid*52+51] = 0.f;   // zero pad -> masking-free k_scan
  __syncthreads();
  float4* dst = (float4*)(w_ws + (size_t)blockIdx.x*128*52);
  const float4* src = (const float4*)wt;
  for (int li = tid; li < 1664; li += 128) dst[li] = src[li];
}

// =====================================================================
// K-cvt: qa_tab f32 -> bf16  AND  Wcomb = [We|Wa] f32 -> bf16  (unchanged)
// =====================================================================
__global__ __launch_bounds__(256) void k_cvt(
    const float* __restrict__ qa_tab, const float* __restrict__ We,
    const float* __restrict__ Wa, uint16_t* __restrict__ qa_bf,
    uint16_t* __restrict__ wcomb)
{
  const size_t n_qa4 = 6400064;            // 100001*256/4
  const size_t n_w4  = 32768;              // 512*256/4
  size_t stride = (size_t)gridDim.x*blockDim.x;
  for (size_t i = (size_t)blockIdx.x*256 + threadIdx.x; i < n_qa4 + n_w4; i += stride){
    float4 v;
    if (i < n_qa4){
      v = ((const float4*)qa_tab)[i];
      ushort4 o; o.x=f2b(v.x); o.y=f2b(v.y); o.z=f2b(v.z); o.w=f2b(v.w);
      ((ushort4*)qa_bf)[i] = o;
    } else {
      size_t j = i - n_qa4;                // float4 index into Wcomb [512][256]
      size_t f = j*4;
      int col = (int)(f >> 8), k = (int)(f & 255);
      const float* srcp = (col < 256) ? (We + (size_t)col*256 + k)
                                      : (Wa + (size_t)(col-256)*256 + k);
      v = *(const float4*)srcp;
      ushort4 o; o.x=f2b(v.x); o.y=f2b(v.y); o.z=f2b(v.z); o.w=f2b(v.w);
      ((ushort4*)wcomb)[j] = o;
    }
  }
}

// =====================================================================
// K-cvt2 (after k_scan, into dead w_ws region): q_tab -> q_bf, Wr -> wr_bf
// =====================================================================
__global__ __launch_bounds__(256) void k_cvt2(
    const float* __restrict__ q_tab, const float* __restrict__ Wr,
    uint16_t* __restrict__ q_bf, uint16_t* __restrict__ wr_bf)
{
  const size_t n_q4  = 1600032;            // 50001*128/4
  const size_t n_wr4 = 12288;              // 128*384/4
  size_t stride = (size_t)gridDim.x*blockDim.x;
  for (size_t i = (size_t)blockIdx.x*256 + threadIdx.x; i < n_q4 + n_wr4; i += stride){
    if (i < n_q4){
      float4 v = ((const float4*)q_tab)[i];
      ushort4 o; o.x=f2b(v.x); o.y=f2b(v.y); o.z=f2b(v.z); o.w=f2b(v.w);
      ((ushort4*)q_bf)[i] = o;
    } else {
      size_t j = i - n_q4;
      float4 v = ((const float4*)Wr)[j];
      ushort4 o; o.x=f2b(v.x); o.y=f2b(v.y); o.z=f2b(v.z); o.w=f2b(v.w);
      ((ushort4*)wr_bf)[j] = o;
    }
  }
}

// =====================================================================
// K1b: ea via bf16 MFMA; all staging via global_load_lds (unchanged)
// =====================================================================
__global__ __launch_bounds__(256, 2) void k_ea(
    const int* __restrict__ qa_data, const uint16_t* __restrict__ qa_bf,
    const uint16_t* __restrict__ wcomb, const float* __restrict__ be,
    const float* __restrict__ ba, __hip_bfloat16* __restrict__ ea_ws)
{
  __shared__ uint16_t Ab[128*32];
  __shared__ uint16_t Bb[128*32];
  const int tid = threadIdx.x;
  const int lane = tid & 63, wid = tid >> 6;
  const int braw = blockIdx.x;
  const int nb = (braw >> 3) & 3;                      // col-block
  const int mb = (braw & 7) | ((braw >> 5) << 3);      // row-block; siblings: b,b+8,b+16,b+24 -> same XCD (b%8)
  const int rb = mb*128, cb = nb*128;

  const char* qac = (const char*)qa_bf;
  size_t aoff0, aoff1;
  {
    int r0 = wid*32 + (lane>>2);
    aoff0 = (size_t)qa_data[rb + r0]*512      + (size_t)(lane&3)*16;
    aoff1 = (size_t)qa_data[rb + r0 + 16]*512 + (size_t)(lane&3)*16;
  }
  const char* wcb = (const char*)wcomb;
  size_t boff0 = (size_t)(cb + wid*32 + (lane>>2))*512 + (size_t)(lane&3)*16;
  size_t boff1 = boff0 + 16*512;

  const int wr = (wid>>1)*64, wc = (wid&1)*64;
  float bias[4];
  #pragma unroll
  for (int tj=0;tj<4;tj++){
    int colg = cb + wc + tj*16 + (lane&15);
    bias[tj] = (nb<2) ? be[colg] : ba[colg-256];
  }

  f32x4 acc[4][4];
  #pragma unroll
  for (int i=0;i<4;i++){
    #pragma unroll
    for (int j=0;j<4;j++) acc[i][j] = (f32x4)(0.f);
  }

  #pragma unroll 1
  for (int kc=0; kc<8; kc++){
    __syncthreads();
    gl_lds16(qac + aoff0 + (size_t)kc*64, &Ab[(wid*2+0)*512]);
    gl_lds16(qac + aoff1 + (size_t)kc*64, &Ab[(wid*2+1)*512]);
    gl_lds16(wcb + boff0 + (size_t)kc*64, &Bb[(wid*2+0)*512]);
    gl_lds16(wcb + boff1 + (size_t)kc*64, &Bb[(wid*2+1)*512]);
    __syncthreads();
    bf16x8 af[4], bfr[4];
    #pragma unroll
    for (int ti=0;ti<4;ti++)
      af[ti] = *(const bf16x8*)&Ab[(wr + ti*16 + (lane&15))*32 + (lane>>4)*8];
    #pragma unroll
    for (int tj=0;tj<4;tj++)
      bfr[tj] = *(const bf16x8*)&Bb[(wc + tj*16 + (lane&15))*32 + (lane>>4)*8];
    #pragma unroll
    for (int ti=0;ti<4;ti++){
      #pragma unroll
      for (int tj=0;tj<4;tj++)
        acc[ti][tj] = __builtin_amdgcn_mfma_f32_16x16x32_bf16(af[ti], bfr[tj], acc[ti][tj], 0, 0, 0);
    }
  }
  const int rq = (lane>>4)*4, cl = lane&15;
  #pragma unroll
  for (int ti=0;ti<4;ti++){
    #pragma unroll
    for (int r=0;r<4;r++){
      int row = rb + wr + ti*16 + rq + r;
      __hip_bfloat16* orow = ea_ws + (size_t)row*512 + cb + wc;
      #pragma unroll
      for (int tj=0;tj<4;tj++){
        float x = acc[ti][tj][r] + bias[tj];
        float v = (nb<2) ? (1.f/(1.f+__expf(-x)))
                         : (1.f - 2.f/(__expf(2.f*x)+1.f));
        orow[tj*16 + cl] = __float2bfloat16(v);
      }
    }
  }
}

// =====================================================================
// K2 v12: full-m per thread (R5/R6 structure: zero exchange, zero shuffles)
// + w transported via async global_load_lds double-buffered LDS groups.
// R6 post-mortem: SMEM is the wrong pipe for streaming w (104KB/block
// through a 16KB scalar cache shared by 2 CUs -> per-step serialized miss
// round trips, 1900 cyc/step stall). The proven broadcast mechanism in
// this file is k_ea/k_final's staging path:
//   - group g computes from wlds[g&1] (13 ds_read_b128 broadcasts/step;
//     wave-uniform address -> same-address broadcast, no bank conflicts);
//   - group g+1 (2080 B) is staged by threads 0..129 with one gl_lds16
//     each into wlds[(g+1)&1], issued at group-g start -> ~10 steps
//     (>3000 cyc) of slack covers even cold HBM latency;
//   - ONE barrier + vmcnt drain per group (50 total, not 500).
// q gate stays AS4-scalar (2KB, k$-hot now that w left SMEM). e/a packed
// (a16<<16)|e16, prefetched one group ahead (VMEM, coalesced).
// Register demand ~180 (Mv 52 + transient w quads 52 + e/a 20 + misc),
// short w live ranges -> no R5-style spill.
// =====================================================================
__global__ __launch_bounds__(256, 1) void k_scan(
    const int* __restrict__ q_data, const float* __restrict__ w_ws,
    const uint16_t* __restrict__ ea_ws, const float* __restrict__ Mv0,
    __hip_bfloat16* __restrict__ reads_ws)
{
  __shared__ __align__(16) float wlds[2][GSZ*52];   // 2 x 2080 B
  const int tid  = threadIdx.x;
  const int d    = tid;             // 0..255
  const int b    = blockIdx.x;      // 0..255
  const int base = b * TLEN;

  float Mv[52];
  #pragma unroll
  for (int m=0;m<MSZ;m++) Mv[m] = Mv0[(size_t)m*256 + d];
  Mv[50] = 0.f; Mv[51] = 0.f;

  typedef const __attribute__((address_space(4))) int cint;
  cint* qbase = (cint*)q_data + base;

  const char* wsrc = (const char*)(w_ws + (size_t)base*52);
  // stage group 0 into buf0: 2080 B = 130 lanes x 16 B.
  // gl_lds16 dst must be the WAVE-uniform base; HW adds lane*16.
  if (tid < 130)
    gl_lds16(wsrc + (size_t)tid*16, &wlds[0][(tid>>6)*256]);

  uint32_t epk[GSZ], epn[GSZ];
  #pragma unroll
  for (int j=0;j<GSZ;j++){
    uint32_t e16 = ea_ws[(size_t)(base+j)*512 + d];
    uint32_t a16 = ea_ws[(size_t)(base+j)*512 + 256 + d];
    epk[j] = (a16 << 16) | e16;
  }
  asm volatile("s_waitcnt vmcnt(0)");
  __syncthreads();

  #pragma unroll 1
  for (int g=0; g<50; g++){
    if (g < 49){
      // stage group g+1 into the other buffer (issued early; consumed
      // only after this group's end-of-group vmcnt+barrier)
      if (tid < 130)
        gl_lds16(wsrc + (size_t)(g+1)*2080 + (size_t)tid*16,
                 &wlds[(g+1)&1][(tid>>6)*256]);
      const int sn = base + (g+1)*GSZ;
      #pragma unroll
      for (int j=0;j<GSZ;j++){
        uint32_t e16 = ea_ws[(size_t)(sn+j)*512 + d];
        uint32_t a16 = ea_ws[(size_t)(sn+j)*512 + 256 + d];
        epn[j] = (a16 << 16) | e16;
      }
    }
    int qv[GSZ];
    #pragma unroll
    for (int j=0;j<GSZ;j++) qv[j] = qbase[g*GSZ + j];   // scalar gate (k$-hot)

    const float* wb = wlds[g&1];
    #pragma unroll
    for (int jj=0; jj<GSZ; jj++){
      const f32x4* wq = (const f32x4*)(wb + jj*52);   // uniform addr -> broadcast
      const uint32_t p = epk[jj];
      union { uint32_t u; float f; } ue_, ua_;
      ue_.u = p << 16; ua_.u = p & 0xffff0000u;
      const float ef = ue_.f, af = ua_.f;

      f32x4 wv[13];
      #pragma unroll
      for (int qq=0;qq<13;qq++) wv[qq] = wq[qq];

      float r0=0.f, r1=0.f, r2=0.f, r3=0.f;
      #pragma unroll
      for (int qq=0;qq<13;qq++){
        r0 = fmaf(wv[qq].x, Mv[qq*4+0], r0);
        r1 = fmaf(wv[qq].y, Mv[qq*4+1], r1);
        r2 = fmaf(wv[qq].z, Mv[qq*4+2], r2);
        r3 = fmaf(wv[qq].w, Mv[qq*4+3], r3);
      }
      reads_ws[(size_t)(base + g*GSZ + jj)*256 + d] =
          __float2bfloat16((r0+r1)+(r2+r3));

      if (qv[jj] > 0){   // uniform branch (q==0 rare)
        #pragma unroll
        for (int qq=0;qq<13;qq++){
          { float tt = fmaf(ef, Mv[qq*4+0], -af); Mv[qq*4+0] = fmaf(-wv[qq].x, tt, Mv[qq*4+0]); }
          { float tt = fmaf(ef, Mv[qq*4+1], -af); Mv[qq*4+1] = fmaf(-wv[qq].y, tt, Mv[qq*4+1]); }
          { float tt = fmaf(ef, Mv[qq*4+2], -af); Mv[qq*4+2] = fmaf(-wv[qq].z, tt, Mv[qq*4+2]); }
          { float tt = fmaf(ef, Mv[qq*4+3], -af); Mv[qq*4+3] = fmaf(-wv[qq].w, tt, Mv[qq*4+3]); }
        }
      }
    }

    if (g < 49){
      #pragma unroll
      for (int j=0;j<GSZ;j++) epk[j] = epn[j];
    }
    // drain staging (vmcnt) then sync: (a) buf[(g+1)&1] fully written
    // before group g+1 reads it; (b) all waves done reading buf[g&1]
    // before group g+1 re-stages into it.
    asm volatile("s_waitcnt vmcnt(0)");
    __syncthreads();
  }
}

// =====================================================================
// K3 v3: bf16 MFMA, all staging via global_load_lds (unchanged)
// =====================================================================
__global__ __launch_bounds__(256, 2) void k_final(
    const int* __restrict__ q_data, const uint16_t* __restrict__ q_bf,
    const uint16_t* __restrict__ reads16, const uint16_t* __restrict__ wr_bf,
    const float* __restrict__ br, const float* __restrict__ Wp,
    const float* __restrict__ bp, const float* __restrict__ target,
    float* __restrict__ out, float* __restrict__ parts)
{
  __shared__ uint16_t Ab[64*32];    // 4 KB
  __shared__ uint16_t Bb[128*32];   // 8 KB
  __shared__ float redbuf[8];
  const int tid = threadIdx.x;
  const int lane = tid & 63, wid = tid >> 6;
  const int rb = blockIdx.x * 64;

  const char* rdc = (const char*)reads16;
  const char* qbc = (const char*)q_bf;
  const char* wrc = (const char*)wr_bf;
  const int arow = wid*16 + (lane>>2);
  size_t aoff_r = (size_t)(rb+arow)*512 + (size_t)(lane&3)*16;
  size_t aoff_q = (size_t)q_data[rb+arow]*256 + (size_t)(lane&3)*16;
  size_t boff0  = (size_t)(wid*32 + (lane>>2))*768 + (size_t)(lane&3)*16;
  size_t boff1  = boff0 + 16*768;

  f32x4 acc[8];
  #pragma unroll
  for (int tj=0;tj<8;tj++) acc[tj] = (f32x4)(0.f);

  #pragma unroll 1
  for (int kc=0; kc<12; kc++){
    __syncthreads();
    if (kc < 8) gl_lds16(rdc + aoff_r + (size_t)kc*64,     &Ab[wid*512]);
    else        gl_lds16(qbc + aoff_q + (size_t)(kc-8)*64, &Ab[wid*512]);
    gl_lds16(wrc + boff0 + (size_t)kc*64, &Bb[(wid*2+0)*512]);
    gl_lds16(wrc + boff1 + (size_t)kc*64, &Bb[(wid*2+1)*512]);
    __syncthreads();
    bf16x8 af = *(const bf16x8*)&Ab[(wid*16 + (lane&15))*32 + (lane>>4)*8];
    #pragma unroll
    for (int tj=0;tj<8;tj++){
      bf16x8 bf = *(const bf16x8*)&Bb[(tj*16 + (lane&15))*32 + (lane>>4)*8];
      acc[tj] = __builtin_amdgcn_mfma_f32_16x16x32_bf16(af, bf, acc[tj], 0, 0, 0);
    }
  }
  const int cl = lane & 15, rq = lane >> 4;
  float p[4] = {0.f,0.f,0.f,0.f};
  #pragma unroll
  for (int tj=0;tj<8;tj++){
    int cg = tj*16 + cl;
    float brv = br[cg], wpv = Wp[cg];
    #pragma unroll
    for (int r=0;r<4;r++){
      float x = acc[tj][r] + brv;
      float hh = 1.f - 2.f/(__expf(2.f*x)+1.f);
      p[r] = fmaf(hh, wpv, p[r]);
    }
  }
  #pragma unroll
  for (int off=1; off<16; off<<=1){
    #pragma unroll
    for (int r=0;r<4;r++) p[r] += __shfl_xor(p[r], off);
  }
  float bpv = bp[0];
  float lsum = 0.f, csum = 0.f;
  if (cl == 0){
    #pragma unroll
    for (int r=0;r<4;r++){
      int row = rb + wid*16 + rq*4 + r;
      float pred = p[r] + bpv;
      out[1 + row] = 1.f/(1.f + __expf(-pred));
      float tg = target[row];
      if (tg >= 0.f){
        lsum += fmaxf(pred, 0.f) - pred*tg + log1pf(__expf(-fabsf(pred)));
        csum += 1.f;
      }
    }
  }
  #pragma unroll
  for (int off=16; off<64; off<<=1){
    lsum += __shfl_xor(lsum, off);
    csum += __shfl_xor(csum, off);
  }
  if (lane == 0){ redbuf[wid*2] = lsum; redbuf[wid*2+1] = csum; }
  __syncthreads();
  if (tid == 0){
    parts[blockIdx.x]        = redbuf[0]+redbuf[2]+redbuf[4]+redbuf[6];
    parts[2000 + blockIdx.x] = redbuf[1]+redbuf[3]+redbuf[5]+redbuf[7];
  }
}

// =====================================================================
// K4: final loss reduction (unchanged)
// =====================================================================
__global__ __launch_bounds__(256) void k_loss(
    const float* __restrict__ parts, float* __restrict__ out)
{
  __shared__ float red[8];
  const int tid = threadIdx.x;
  float l = 0.f, cn = 0.f;
  for (int i = tid; i < 2000; i += 256){ l += parts[i]; cn += parts[2000+i]; }
  #pragma unroll
  for (int off=32; off>0; off>>=1){ l += __shfl_xor(l, off); cn += __shfl_xor(cn, off); }
  if ((tid & 63) == 0){ red[(tid>>6)*2] = l; red[(tid>>6)*2+1] = cn; }
  __syncthreads();
  if (tid == 0){
    float L = red[0]+red[2]+red[4]+red[6];
    float C = red[1]+red[3]+red[5]+red[7];
    out[0] = L / fmaxf(C, 1.f);
  }
}

// =====================================================================
extern "C" void kernel_launch(void* const* d_in, const int* in_sizes, int n_in,
                              void* d_out, int out_size, void* d_ws, size_t ws_size,
                              hipStream_t stream) {
  const int*   q_data  = (const int*)d_in[0];
  const int*   qa_data = (const int*)d_in[1];
  const float* target  = (const float*)d_in[2];
  const float* q_tab   = (const float*)d_in[3];
  const float* qa_tab  = (const float*)d_in[4];
  const float* Mk  = (const float*)d_in[5];
  const float* Mv0 = (const float*)d_in[6];
  const float* We  = (const float*)d_in[7];
  const float* be  = (const float*)d_in[8];
  const float* Wa  = (const float*)d_in[9];
  const float* ba  = (const float*)d_in[10];
  const float* Wr  = (const float*)d_in[11];
  const float* br  = (const float*)d_in[12];
  const float* Wp  = (const float*)d_in[13];
  const float* bp  = (const float*)d_in[14];

  char* ws = (char*)d_ws;
  float*          w_ws     = (float*)ws;                           // [0, 26,624,000)
  __hip_bfloat16* ea_ws    = (__hip_bfloat16*)(ws + 26624000);     // 131,072,000 B
  uint16_t*       qa_bf    = (uint16_t*)(ws + 157696000);          // 51,200,512 B
  uint16_t*       wcomb    = (uint16_t*)(ws + 208896512);          // 262,144 B
  __hip_bfloat16* reads_ws = (__hip_bfloat16*)(ws + 157696000);    // 65,536,000 B (after k_ea)
  float*          parts    = (float*)ws;                           // 16,000 B (after k_scan)
  uint16_t*       q_bf     = (uint16_t*)(ws + 2000000);            // 12,800,256 B (after k_scan)
  uint16_t*       wr_bf    = (uint16_t*)(ws + 16000000);           // 98,304 B (after k_scan)

  float* out = (float*)d_out;   // f32: [loss, probs(128000)]

  k_w    <<<1000, 128, 0, stream>>>(q_data, q_tab, Mk, w_ws);
  k_cvt  <<<2048, 256, 0, stream>>>(qa_tab, We, Wa, qa_bf, wcomb);
  k_ea   <<<4000, 256, 0, stream>>>(qa_data, qa_bf, wcomb, be, ba, ea_ws);
  k_scan <<<256,  256, 0, stream>>>(q_data, w_ws, (const uint16_t*)ea_ws, Mv0, reads_ws);
  k_cvt2 <<<1024, 256, 0, stream>>>(q_tab, Wr, q_bf, wr_bf);
  k_final<<<2000, 256, 0, stream>>>(q_data, q_bf, (const uint16_t*)reads_ws, wr_bf, br, Wp, bp, target, out, parts);
  k_loss <<<1,    256, 0, stream>>>(parts, out);
}

// Round 8
// 613.106 us; speedup vs baseline: 1.4045x; 1.1444x over previous
//
#include <hip/hip_runtime.h>
#include <hip/hip_bf16.h>
#include <stdint.h>

// DTYPE CONTRACT (locked R3): inputs f32, output f32 [loss, probs(128000)].
// WS MAP (223,248,000 B budget proven R3):
//   [0, 26.6M)        w_ws fp32 [row][52]  (k_w -> k_scan); after k_scan dead:
//                       parts @ +0 (16KB), wr_bf @ +16.0M, q_bf @ +2.0M (k_cvt2 -> k_final)
//   [26.6M, 157.7M)   ea_ws bf16 [row][512] (k_ea -> k_scan)
//   [157.7M, 223.2M)   union: qa_bf (51.2M) + Wcomb bf16 (256KB) (k_cvt -> k_ea),
//                     then reads_ws bf16 (k_scan -> k_final)

#define BATCH 256
#define TLEN  500
#define DKQ   128
#define DVV   256
#define MSZ   50
#define NROWS 128000
#define GSZ   10

__device__ __forceinline__ float bfs(uint16_t u){
  union { uint32_t u; float f; } v; v.u = ((uint32_t)u) << 16; return v.f;
}
__device__ __forceinline__ uint16_t f2b(float x){
  union { __hip_bfloat16 h; uint16_t u; } c; c.h = __float2bfloat16(x); return c.u;
}

typedef __attribute__((ext_vector_type(8))) short bf16x8;
typedef __attribute__((ext_vector_type(4))) float f32x4;

__device__ __forceinline__ void gl_lds16(const void* g, void* l){
  __builtin_amdgcn_global_load_lds(
      (const __attribute__((address_space(1))) void*)g,
      (__attribute__((address_space(3))) void*)l, 16, 0, 0);
}

// =====================================================================
// K1a: w = softmax(q_e @ Mk^T) -> w_ws fp32 [row][52]  (unchanged)
// =====================================================================
__global__ __launch_bounds__(128, 1) void k_w(
    const int* __restrict__ q_data, const float* __restrict__ q_tab,
    const float* __restrict__ Mk, float* __restrict__ w_ws)
{
  __shared__ float mk[MSZ*DKQ];
  __shared__ float wt[128*52];
  const int tid = threadIdx.x;
  for (int li = tid; li < 1600; li += 128)
    ((float4*)mk)[li] = ((const float4*)Mk)[li];
  __syncthreads();

  const int row = blockIdx.x*128 + tid;
  const int qi = q_data[row];
  const float4* qrow = (const float4*)(q_tab + (size_t)qi*DKQ);

  float acc[MSZ];
  #pragma unroll
  for (int m=0;m<MSZ;m++) acc[m] = 0.f;

  #pragma unroll 1
  for (int c8=0; c8<8; c8++){
    float4 q0 = qrow[c8*4+0], q1 = qrow[c8*4+1], q2 = qrow[c8*4+2], q3 = qrow[c8*4+3];
    #pragma unroll
    for (int m=0;m<MSZ;m++){
      const float4* mr = (const float4*)&mk[m*DKQ + c8*16];
      float4 a = mr[0], b = mr[1], cc = mr[2], d = mr[3];
      float s = acc[m];
      s = fmaf(q0.x,a.x,s);  s = fmaf(q0.y,a.y,s);  s = fmaf(q0.z,a.z,s);  s = fmaf(q0.w,a.w,s);
      s = fmaf(q1.x,b.x,s);  s = fmaf(q1.y,b.y,s);  s = fmaf(q1.z,b.z,s);  s = fmaf(q1.w,b.w,s);
      s = fmaf(q2.x,cc.x,s); s = fmaf(q2.y,cc.y,s); s = fmaf(q2.z,cc.z,s); s = fmaf(q2.w,cc.w,s);
      s = fmaf(q3.x,d.x,s);  s = fmaf(q3.y,d.y,s);  s = fmaf(q3.z,d.z,s);  s = fmaf(q3.w,d.w,s);
      acc[m] = s;
    }
  }
  float mx = acc[0];
  #pragma unroll
  for (int m=1;m<MSZ;m++) mx = fmaxf(mx, acc[m]);
  float s = 0.f;
  #pragma unroll
  for (int m=0;m<MSZ;m++){ acc[m] = __expf(acc[m]-mx); s += acc[m]; }
  float inv = 1.0f / s;
  #pragma unroll
  for (int m=0;m<MSZ;m++) wt[tid*52+m] = acc[m]*inv;
  wt[tid*52+50] = 0.f; wt[tid*52+51] = 0.f;   // zero pad -> masking-free k_scan
  __syncthreads();
  float4* dst = (float4*)(w_ws + (size_t)blockIdx.x*128*52);
  const float4* src = (const float4*)wt;
  for (int li = tid; li < 1664; li += 128) dst[li] = src[li];
}

// =====================================================================
// K-cvt: qa_tab f32 -> bf16  AND  Wcomb = [We|Wa] f32 -> bf16  (unchanged)
// =====================================================================
__global__ __launch_bounds__(256) void k_cvt(
    const float* __restrict__ qa_tab, const float* __restrict__ We,
    const float* __restrict__ Wa, uint16_t* __restrict__ qa_bf,
    uint16_t* __restrict__ wcomb)
{
  const size_t n_qa4 = 6400064;            // 100001*256/4
  const size_t n_w4  = 32768;              // 512*256/4
  size_t stride = (size_t)gridDim.x*blockDim.x;
  for (size_t i = (size_t)blockIdx.x*256 + threadIdx.x; i < n_qa4 + n_w4; i += stride){
    float4 v;
    if (i < n_qa4){
      v = ((const float4*)qa_tab)[i];
      ushort4 o; o.x=f2b(v.x); o.y=f2b(v.y); o.z=f2b(v.z); o.w=f2b(v.w);
      ((ushort4*)qa_bf)[i] = o;
    } else {
      size_t j = i - n_qa4;                // float4 index into Wcomb [512][256]
      size_t f = j*4;
      int col = (int)(f >> 8), k = (int)(f & 255);
      const float* srcp = (col < 256) ? (We + (size_t)col*256 + k)
                                      : (Wa + (size_t)(col-256)*256 + k);
      v = *(const float4*)srcp;
      ushort4 o; o.x=f2b(v.x); o.y=f2b(v.y); o.z=f2b(v.z); o.w=f2b(v.w);
      ((ushort4*)wcomb)[j] = o;
    }
  }
}

// =====================================================================
// K-cvt2 (after k_scan, into dead w_ws region): q_tab -> q_bf, Wr -> wr_bf
// =====================================================================
__global__ __launch_bounds__(256) void k_cvt2(
    const float* __restrict__ q_tab, const float* __restrict__ Wr,
    uint16_t* __restrict__ q_bf, uint16_t* __restrict__ wr_bf)
{
  const size_t n_q4  = 1600032;            // 50001*128/4
  const size_t n_wr4 = 12288;              // 128*384/4
  size_t stride = (size_t)gridDim.x*blockDim.x;
  for (size_t i = (size_t)blockIdx.x*256 + threadIdx.x; i < n_q4 + n_wr4; i += stride){
    if (i < n_q4){
      float4 v = ((const float4*)q_tab)[i];
      ushort4 o; o.x=f2b(v.x); o.y=f2b(v.y); o.z=f2b(v.z); o.w=f2b(v.w);
      ((ushort4*)q_bf)[i] = o;
    } else {
      size_t j = i - n_q4;
      float4 v = ((const float4*)Wr)[j];
      ushort4 o; o.x=f2b(v.x); o.y=f2b(v.y); o.z=f2b(v.z); o.w=f2b(v.w);
      ((ushort4*)wr_bf)[j] = o;
    }
  }
}

// =====================================================================
// K1b: ea via bf16 MFMA; all staging via global_load_lds (unchanged)
// =====================================================================
__global__ __launch_bounds__(256, 2) void k_ea(
    const int* __restrict__ qa_data, const uint16_t* __restrict__ qa_bf,
    const uint16_t* __restrict__ wcomb, const float* __restrict__ be,
    const float* __restrict__ ba, __hip_bfloat16* __restrict__ ea_ws)
{
  __shared__ uint16_t Ab[128*32];
  __shared__ uint16_t Bb[128*32];
  const int tid = threadIdx.x;
  const int lane = tid & 63, wid = tid >> 6;
  const int braw = blockIdx.x;
  const int nb = (braw >> 3) & 3;                      // col-block
  const int mb = (braw & 7) | ((braw >> 5) << 3);      // row-block; siblings: b,b+8,b+16,b+24 -> same XCD (b%8)
  const int rb = mb*128, cb = nb*128;

  const char* qac = (const char*)qa_bf;
  size_t aoff0, aoff1;
  {
    int r0 = wid*32 + (lane>>2);
    aoff0 = (size_t)qa_data[rb + r0]*512      + (size_t)(lane&3)*16;
    aoff1 = (size_t)qa_data[rb + r0 + 16]*512 + (size_t)(lane&3)*16;
  }
  const char* wcb = (const char*)wcomb;
  size_t boff0 = (size_t)(cb + wid*32 + (lane>>2))*512 + (size_t)(lane&3)*16;
  size_t boff1 = boff0 + 16*512;

  const int wr = (wid>>1)*64, wc = (wid&1)*64;
  float bias[4];
  #pragma unroll
  for (int tj=0;tj<4;tj++){
    int colg = cb + wc + tj*16 + (lane&15);
    bias[tj] = (nb<2) ? be[colg] : ba[colg-256];
  }

  f32x4 acc[4][4];
  #pragma unroll
  for (int i=0;i<4;i++){
    #pragma unroll
    for (int j=0;j<4;j++) acc[i][j] = (f32x4)(0.f);
  }

  #pragma unroll 1
  for (int kc=0; kc<8; kc++){
    __syncthreads();
    gl_lds16(qac + aoff0 + (size_t)kc*64, &Ab[(wid*2+0)*512]);
    gl_lds16(qac + aoff1 + (size_t)kc*64, &Ab[(wid*2+1)*512]);
    gl_lds16(wcb + boff0 + (size_t)kc*64, &Bb[(wid*2+0)*512]);
    gl_lds16(wcb + boff1 + (size_t)kc*64, &Bb[(wid*2+1)*512]);
    __syncthreads();
    bf16x8 af[4], bfr[4];
    #pragma unroll
    for (int ti=0;ti<4;ti++)
      af[ti] = *(const bf16x8*)&Ab[(wr + ti*16 + (lane&15))*32 + (lane>>4)*8];
    #pragma unroll
    for (int tj=0;tj<4;tj++)
      bfr[tj] = *(const bf16x8*)&Bb[(wc + tj*16 + (lane&15))*32 + (lane>>4)*8];
    #pragma unroll
    for (int ti=0;ti<4;ti++){
      #pragma unroll
      for (int tj=0;tj<4;tj++)
        acc[ti][tj] = __builtin_amdgcn_mfma_f32_16x16x32_bf16(af[ti], bfr[tj], acc[ti][tj], 0, 0, 0);
    }
  }
  const int rq = (lane>>4)*4, cl = lane&15;
  #pragma unroll
  for (int ti=0;ti<4;ti++){
    #pragma unroll
    for (int r=0;r<4;r++){
      int row = rb + wr + ti*16 + rq + r;
      __hip_bfloat16* orow = ea_ws + (size_t)row*512 + cb + wc;
      #pragma unroll
      for (int tj=0;tj<4;tj++){
        float x = acc[ti][tj][r] + bias[tj];
        float v = (nb<2) ? (1.f/(1.f+__expf(-x)))
                         : (1.f - 2.f/(__expf(2.f*x)+1.f));
        orow[tj*16 + cl] = __float2bfloat16(v);
      }
    }
  }
}

// =====================================================================
// K2 v13: IN-WAVE 2-way m-split + LDS-staged w + 2 waves/SIMD.
// Ledger: R0 (2 w/SIMD, per-step barrier) 264us beats every 1-wave/SIMD
// variant (R5 373 / R6 473 / R7 328) -> occupancy is the dominant term.
// R7's residual: VGPR 96 < Mv52+wv52 -> chunked ds_reads with serialized
// lgkm waits, unhidden at 1 wave/SIMD.
// This version removes BOTH limits:
//   - m-split h = lane>>5 INSIDE the wave: h0 owns m0..27, h1 m28..51.
//     Partial-read reduction = ONE __shfl_xor(rp,32). Zero barriers for
//     exchange, zero LDS exchange, and per-lane regs halve (Mv 28 + wv 28
//     ~ 90 VGPR -> no chunking).
//   - each wave covers 32 d's (2 lanes per d); 256-thr block = 128 d's;
//     grid 512 = (256 b) x (2 dblk) = 2 blocks/CU = 2 waves/SIMD.
//   - w via R7's proven gl_lds16-staged LDS double buffer; per step each
//     wave issues 7 ds_read_b128 at TWO addresses (h*112 apart) = free
//     2-way aliasing. h1's 7th quad over-reads into a 4-float LDS pad ->
//     cndmask'd to 0 (w pads m50/51 are genuinely 0 from k_w).
//   - one vmcnt(0)+barrier per 10-step group (staging sync only).
//   - q gate AS4-scalar (R4-proven); e/a packed u32, group-ahead prefetch.
// =====================================================================
__global__ __launch_bounds__(256, 2) void k_scan(
    const int* __restrict__ q_data, const float* __restrict__ w_ws,
    const uint16_t* __restrict__ ea_ws, const float* __restrict__ Mv0,
    __hip_bfloat16* __restrict__ reads_ws)
{
  __shared__ __align__(16) float wlds[2][GSZ*52 + 4];   // +4 pad: h1 tail over-read
  const int tid  = threadIdx.x;
  const int lane = tid & 63;
  const int wid  = tid >> 6;              // 0..3
  const int h    = lane >> 5;             // in-wave m-half
  const int b    = blockIdx.x & 255;      // siblings bid,bid+256 -> same XCD (mod 8)
  const int dblk = blockIdx.x >> 8;
  const int d    = dblk*128 + wid*32 + (lane & 31);
  const int base = b * TLEN;

  // this lane's 28 m-slots: m = h*28+i  (h1: i>=22 -> m>=50: Mv=0, w=0)
  float Mv[28];
  #pragma unroll
  for (int i=0;i<28;i++){
    int m = h*28 + i;
    Mv[i] = (m < MSZ) ? Mv0[(size_t)m*256 + d] : 0.f;
  }

  typedef const __attribute__((address_space(4))) int cint;
  cint* qbase = (cint*)q_data + base;

  const char* wsrc = (const char*)(w_ws + (size_t)base*52);
  // stage group 0 (2080 B = 130 lanes x 16 B); gl_lds16 dst = wave-uniform
  // base, HW adds lane*16.
  if (tid < 130)
    gl_lds16(wsrc + (size_t)tid*16, &wlds[0][(tid>>6)*256]);

  uint32_t epk[GSZ], epn[GSZ];
  #pragma unroll
  for (int j=0;j<GSZ;j++){
    uint32_t e16 = ea_ws[(size_t)(base+j)*512 + d];
    uint32_t a16 = ea_ws[(size_t)(base+j)*512 + 256 + d];
    epk[j] = (a16 << 16) | e16;
  }
  asm volatile("s_waitcnt vmcnt(0)");
  __syncthreads();

  #pragma unroll 1
  for (int g=0; g<50; g++){
    if (g < 49){
      if (tid < 130)
        gl_lds16(wsrc + (size_t)(g+1)*2080 + (size_t)tid*16,
                 &wlds[(g+1)&1][(tid>>6)*256]);
      const int sn = base + (g+1)*GSZ;
      #pragma unroll
      for (int j=0;j<GSZ;j++){
        uint32_t e16 = ea_ws[(size_t)(sn+j)*512 + d];
        uint32_t a16 = ea_ws[(size_t)(sn+j)*512 + 256 + d];
        epn[j] = (a16 << 16) | e16;
      }
    }
    int qv[GSZ];
    #pragma unroll
    for (int j=0;j<GSZ;j++) qv[j] = qbase[g*GSZ + j];   // scalar gate (k$-hot)

    const float* wbuf = wlds[g&1];
    #pragma unroll
    for (int jj=0; jj<GSZ; jj++){
      // 7 b128 broadcasts; two addrs/wave (h*112 apart) = free 2-way alias
      const f32x4* wq = (const f32x4*)(wbuf + jj*52 + h*28);
      f32x4 w0=wq[0], w1=wq[1], w2=wq[2], w3=wq[3], w4=wq[4], w5=wq[5], w6=wq[6];
      if (h) w6 = (f32x4)(0.f);   // h1 quad 6 = m52..55 (pad region) -> zero

      const uint32_t p = epk[jj];
      union { uint32_t u; float f; } ue_, ua_;
      ue_.u = p << 16; ua_.u = p & 0xffff0000u;
      const float ef = ue_.f, af = ua_.f;

      float r0=0.f, r1=0.f, r2=0.f, r3=0.f;
      r0=fmaf(w0.x,Mv[0],r0);  r1=fmaf(w0.y,Mv[1],r1);  r2=fmaf(w0.z,Mv[2],r2);  r3=fmaf(w0.w,Mv[3],r3);
      r0=fmaf(w1.x,Mv[4],r0);  r1=fmaf(w1.y,Mv[5],r1);  r2=fmaf(w1.z,Mv[6],r2);  r3=fmaf(w1.w,Mv[7],r3);
      r0=fmaf(w2.x,Mv[8],r0);  r1=fmaf(w2.y,Mv[9],r1);  r2=fmaf(w2.z,Mv[10],r2); r3=fmaf(w2.w,Mv[11],r3);
      r0=fmaf(w3.x,Mv[12],r0); r1=fmaf(w3.y,Mv[13],r1); r2=fmaf(w3.z,Mv[14],r2); r3=fmaf(w3.w,Mv[15],r3);
      r0=fmaf(w4.x,Mv[16],r0); r1=fmaf(w4.y,Mv[17],r1); r2=fmaf(w4.z,Mv[18],r2); r3=fmaf(w4.w,Mv[19],r3);
      r0=fmaf(w5.x,Mv[20],r0); r1=fmaf(w5.y,Mv[21],r1); r2=fmaf(w5.z,Mv[22],r2); r3=fmaf(w5.w,Mv[23],r3);
      r0=fmaf(w6.x,Mv[24],r0); r1=fmaf(w6.y,Mv[25],r1); r2=fmaf(w6.z,Mv[26],r2); r3=fmaf(w6.w,Mv[27],r3);
      float rp = (r0+r1)+(r2+r3);
      float rs = rp + __shfl_xor(rp, 32);   // cross-half, in-wave
      if (h == 0)
        reads_ws[(size_t)(base + g*GSZ + jj)*256 + d] = __float2bfloat16(rs);

      if (qv[jj] > 0){   // uniform branch (q==0 rare)
        #define UPD(W, I) { float tt = fmaf(ef, Mv[I], -af); Mv[I] = fmaf(-(W), tt, Mv[I]); }
        UPD(w0.x,0)  UPD(w0.y,1)  UPD(w0.z,2)  UPD(w0.w,3)
        UPD(w1.x,4)  UPD(w1.y,5)  UPD(w1.z,6)  UPD(w1.w,7)
        UPD(w2.x,8)  UPD(w2.y,9)  UPD(w2.z,10) UPD(w2.w,11)
        UPD(w3.x,12) UPD(w3.y,13) UPD(w3.z,14) UPD(w3.w,15)
        UPD(w4.x,16) UPD(w4.y,17) UPD(w4.z,18) UPD(w4.w,19)
        UPD(w5.x,20) UPD(w5.y,21) UPD(w5.z,22) UPD(w5.w,23)
        UPD(w6.x,24) UPD(w6.y,25) UPD(w6.z,26) UPD(w6.w,27)
        #undef UPD
      }
    }

    if (g < 49){
      #pragma unroll
      for (int j=0;j<GSZ;j++) epk[j] = epn[j];
    }
    // drain staging then sync: buf[(g+1)&1] fully written before group g+1
    // reads it; all waves done with buf[g&1] before it is re-staged.
    asm volatile("s_waitcnt vmcnt(0)");
    __syncthreads();
  }
}

// =====================================================================
// K3 v3: bf16 MFMA, all staging via global_load_lds (unchanged)
// =====================================================================
__global__ __launch_bounds__(256, 2) void k_final(
    const int* __restrict__ q_data, const uint16_t* __restrict__ q_bf,
    const uint16_t* __restrict__ reads16, const uint16_t* __restrict__ wr_bf,
    const float* __restrict__ br, const float* __restrict__ Wp,
    const float* __restrict__ bp, const float* __restrict__ target,
    float* __restrict__ out, float* __restrict__ parts)
{
  __shared__ uint16_t Ab[64*32];    // 4 KB
  __shared__ uint16_t Bb[128*32];   // 8 KB
  __shared__ float redbuf[8];
  const int tid = threadIdx.x;
  const int lane = tid & 63, wid = tid >> 6;
  const int rb = blockIdx.x * 64;

  const char* rdc = (const char*)reads16;
  const char* qbc = (const char*)q_bf;
  const char* wrc = (const char*)wr_bf;
  const int arow = wid*16 + (lane>>2);
  size_t aoff_r = (size_t)(rb+arow)*512 + (size_t)(lane&3)*16;
  size_t aoff_q = (size_t)q_data[rb+arow]*256 + (size_t)(lane&3)*16;
  size_t boff0  = (size_t)(wid*32 + (lane>>2))*768 + (size_t)(lane&3)*16;
  size_t boff1  = boff0 + 16*768;

  f32x4 acc[8];
  #pragma unroll
  for (int tj=0;tj<8;tj++) acc[tj] = (f32x4)(0.f);

  #pragma unroll 1
  for (int kc=0; kc<12; kc++){
    __syncthreads();
    if (kc < 8) gl_lds16(rdc + aoff_r + (size_t)kc*64,     &Ab[wid*512]);
    else        gl_lds16(qbc + aoff_q + (size_t)(kc-8)*64, &Ab[wid*512]);
    gl_lds16(wrc + boff0 + (size_t)kc*64, &Bb[(wid*2+0)*512]);
    gl_lds16(wrc + boff1 + (size_t)kc*64, &Bb[(wid*2+1)*512]);
    __syncthreads();
    bf16x8 af = *(const bf16x8*)&Ab[(wid*16 + (lane&15))*32 + (lane>>4)*8];
    #pragma unroll
    for (int tj=0;tj<8;tj++){
      bf16x8 bf = *(const bf16x8*)&Bb[(tj*16 + (lane&15))*32 + (lane>>4)*8];
      acc[tj] = __builtin_amdgcn_mfma_f32_16x16x32_bf16(af, bf, acc[tj], 0, 0, 0);
    }
  }
  const int cl = lane & 15, rq = lane >> 4;
  float p[4] = {0.f,0.f,0.f,0.f};
  #pragma unroll
  for (int tj=0;tj<8;tj++){
    int cg = tj*16 + cl;
    float brv = br[cg], wpv = Wp[cg];
    #pragma unroll
    for (int r=0;r<4;r++){
      float x = acc[tj][r] + brv;
      float hh = 1.f - 2.f/(__expf(2.f*x)+1.f);
      p[r] = fmaf(hh, wpv, p[r]);
    }
  }
  #pragma unroll
  for (int off=1; off<16; off<<=1){
    #pragma unroll
    for (int r=0;r<4;r++) p[r] += __shfl_xor(p[r], off);
  }
  float bpv = bp[0];
  float lsum = 0.f, csum = 0.f;
  if (cl == 0){
    #pragma unroll
    for (int r=0;r<4;r++){
      int row = rb + wid*16 + rq*4 + r;
      float pred = p[r] + bpv;
      out[1 + row] = 1.f/(1.f + __expf(-pred));
      float tg = target[row];
      if (tg >= 0.f){
        lsum += fmaxf(pred, 0.f) - pred*tg + log1pf(__expf(-fabsf(pred)));
        csum += 1.f;
      }
    }
  }
  #pragma unroll
  for (int off=16; off<64; off<<=1){
    lsum += __shfl_xor(lsum, off);
    csum += __shfl_xor(csum, off);
  }
  if (lane == 0){ redbuf[wid*2] = lsum; redbuf[wid*2+1] = csum; }
  __syncthreads();
  if (tid == 0){
    parts[blockIdx.x]        = redbuf[0]+redbuf[2]+redbuf[4]+redbuf[6];
    parts[2000 + blockIdx.x] = redbuf[1]+redbuf[3]+redbuf[5]+redbuf[7];
  }
}

// =====================================================================
// K4: final loss reduction (unchanged)
// =====================================================================
__global__ __launch_bounds__(256) void k_loss(
    const float* __restrict__ parts, float* __restrict__ out)
{
  __shared__ float red[8];
  const int tid = threadIdx.x;
  float l = 0.f, cn = 0.f;
  for (int i = tid; i < 2000; i += 256){ l += parts[i]; cn += parts[2000+i]; }
  #pragma unroll
  for (int off=32; off>0; off>>=1){ l += __shfl_xor(l, off); cn += __shfl_xor(cn, off); }
  if ((tid & 63) == 0){ red[(tid>>6)*2] = l; red[(tid>>6)*2+1] = cn; }
  __syncthreads();
  if (tid == 0){
    float L = red[0]+red[2]+red[4]+red[6];
    float C = red[1]+red[3]+red[5]+red[7];
    out[0] = L / fmaxf(C, 1.f);
  }
}

// =====================================================================
extern "C" void kernel_launch(void* const* d_in, const int* in_sizes, int n_in,
                              void* d_out, int out_size, void* d_ws, size_t ws_size,
                              hipStream_t stream) {
  const int*   q_data  = (const int*)d_in[0];
  const int*   qa_data = (const int*)d_in[1];
  const float* target  = (const float*)d_in[2];
  const float* q_tab   = (const float*)d_in[3];
  const float* qa_tab  = (const float*)d_in[4];
  const float* Mk  = (const float*)d_in[5];
  const float* Mv0 = (const float*)d_in[6];
  const float* We  = (const float*)d_in[7];
  const float* be  = (const float*)d_in[8];
  const float* Wa  = (const float*)d_in[9];
  const float* ba  = (const float*)d_in[10];
  const float* Wr  = (const float*)d_in[11];
  const float* br  = (const float*)d_in[12];
  const float* Wp  = (const float*)d_in[13];
  const float* bp  = (const float*)d_in[14];

  char* ws = (char*)d_ws;
  float*          w_ws     = (float*)ws;                           // [0, 26,624,000)
  __hip_bfloat16* ea_ws    = (__hip_bfloat16*)(ws + 26624000);     // 131,072,000 B
  uint16_t*       qa_bf    = (uint16_t*)(ws + 157696000);          // 51,200,512 B
  uint16_t*       wcomb    = (uint16_t*)(ws + 208896512);          // 262,144 B
  __hip_bfloat16* reads_ws = (__hip_bfloat16*)(ws + 157696000);    // 65,536,000 B (after k_ea)
  float*          parts    = (float*)ws;                           // 16,000 B (after k_scan)
  uint16_t*       q_bf     = (uint16_t*)(ws + 2000000);            // 12,800,256 B (after k_scan)
  uint16_t*       wr_bf    = (uint16_t*)(ws + 16000000);           // 98,304 B (after k_scan)

  float* out = (float*)d_out;   // f32: [loss, probs(128000)]

  k_w    <<<1000, 128, 0, stream>>>(q_data, q_tab, Mk, w_ws);
  k_cvt  <<<2048, 256, 0, stream>>>(qa_tab, We, Wa, qa_bf, wcomb);
  k_ea   <<<4000, 256, 0, stream>>>(qa_data, qa_bf, wcomb, be, ba, ea_ws);
  k_scan <<<512,  256, 0, stream>>>(q_data, w_ws, (const uint16_t*)ea_ws, Mv0, reads_ws);
  k_cvt2 <<<1024, 256, 0, stream>>>(q_tab, Wr, q_bf, wr_bf);
  k_final<<<2000, 256, 0, stream>>>(q_data, q_bf, (const uint16_t*)reads_ws, wr_bf, br, Wp, bp, target, out, parts);
  k_loss <<<1,    256, 0, stream>>>(parts, out);
}